// Round 10
// baseline (181.365 us; speedup 1.0000x reference)
//
#include <hip/hip_runtime.h>
#include <hip/hip_bf16.h>
#include <math.h>

// Problem constants
#define B_ 4
#define NQ 5440          // 64*64 + 32*32 + 16*16 + 8*8
#define M_ROWS (B_ * NQ) // 21760
#define NH 8
#define NL 4
#define NP 4
#define HD 32

typedef __attribute__((ext_vector_type(8))) short bf16x8; // 8 bf16 (4 VGPRs)
typedef __attribute__((ext_vector_type(4))) short bf16x4; // 8 bytes
typedef __attribute__((ext_vector_type(4))) float f32x4;
typedef _Float16 f16;

static __device__ __forceinline__ unsigned short f2bf(float f) {
  union { float f; unsigned u; } v; v.f = f;
  unsigned r = (v.u + 0x7fffu + ((v.u >> 16) & 1u)) >> 16; // RNE
  return (unsigned short)r;
}
static __device__ __forceinline__ float bits2f(unsigned u) {
  union { unsigned u; float f; } v; v.u = u; return v.f;
}
// packed fp32x8 -> bf16x8 (targets v_cvt_pk_bf16_f32)
static __device__ __forceinline__ bf16x8 cvt8pk(const float4 a, const float4 b) {
  union { __hip_bfloat162 h2[4]; bf16x8 v; } u;
  u.h2[0] = __float22bfloat162_rn({a.x, a.y});
  u.h2[1] = __float22bfloat162_rn({a.z, a.w});
  u.h2[2] = __float22bfloat162_rn({b.x, b.y});
  u.h2[3] = __float22bfloat162_rn({b.z, b.w});
  return u.v;
}

// ---------------- weight prep only: transpose + convert to bf16 W^T[n][k]
__global__ __launch_bounds__(256) void prep_weights(
    const float* __restrict__ vpw, const float* __restrict__ offw,
    const float* __restrict__ attnw, const float* __restrict__ outw,
    const float* __restrict__ offb, const float* __restrict__ attnb,
    unsigned short* __restrict__ vp_t, unsigned short* __restrict__ q_t,
    unsigned short* __restrict__ out_t, float* __restrict__ biasq) {
  int id = blockIdx.x * 256 + threadIdx.x;
  if (id < 65536) {                       // vp_t[256][256]
    int n = id >> 8, k = id & 255;
    vp_t[id] = f2bf(vpw[k * 256 + n]);
  } else if (id < 163840) {               // q_t[384][256] = [off^T ; attn^T]
    int q = id - 65536; int n = q >> 8, k = q & 255;
    q_t[q] = f2bf(n < 256 ? offw[k * 256 + n] : attnw[k * 128 + (n - 256)]);
  } else if (id < 229376) {               // out_t[256][256]
    int o = id - 163840; int n = o >> 8, k = o & 255;
    out_t[o] = f2bf(outw[k * 256 + n]);
  } else if (id < 229760) {               // biasq[384]
    int j = id - 229376;
    biasq[j] = j < 256 ? offb[j] : attnb[j - 256];
  }
}

// ---------------- GEMM1+2 merged: B-tile in LDS (1 barrier); A read as fp32
// DIRECTLY from the input tensors (no conversion prep-pass) and packed-converted
// to bf16 pre-barrier (cvt latency hides under B staging).
// Block = 128 M x 64 N; wave = 32 M x 64 N via 2x4 mfma_16x16x32.
__global__ __launch_bounds__(256, 3) void gemm12_kernel(
    const float* __restrict__ value, const float* __restrict__ query,
    const unsigned short* __restrict__ wt_vp, const unsigned short* __restrict__ wt_q,
    const float* __restrict__ vp_b, const float* __restrict__ biasq,
    unsigned short* __restrict__ v_bf, f16* __restrict__ offaw_h) {
  __shared__ unsigned short Bs[8 * 64 * 32]; // 32 KB: 8 k-tiles of [64 n][32 k]
  const int t = threadIdx.x;
  const int lane = t & 63, wid = t >> 6;
  const int qd = lane >> 4, l16 = lane & 15;
  // XCD decode: all 10 bn-siblings of a bm-row share g%8 -> same XCD L2
  const int g = blockIdx.x;
  const int grp = g / 80, r = g % 80;
  int by, bx;
  if (grp < 21) { by = grp * 8 + (r & 7); bx = r >> 3; }
  else          { by = 168 + (r & 1);     bx = r >> 1; } // tail: 2 rows x 10 cols
  const int bm = by * 128;
  const bool isv = bx < 4;
  const int bn = isv ? bx * 64 : (bx - 4) * 64;
  const float* A = isv ? value : query;
  const unsigned short* Wt = isv ? wt_vp : wt_q;

  // stage B tile (weights) via async global->LDS
  const unsigned short* bg = Wt + (size_t)(bn + (t >> 2)) * 256 + (t & 3) * 8;
  unsigned short* bs_b = Bs + (t & 192) * 8;
#pragma unroll
  for (int j = 0; j < 8; ++j)
    __builtin_amdgcn_global_load_lds(
        (const __attribute__((address_space(1))) void*)(bg + j * 32),
        (__attribute__((address_space(3))) void*)(bs_b + j * 2048), 16, 0, 0);

  // load + packed-convert A fragments (fp32 -> bf16) before the barrier
  const float* ar0 = A + (size_t)(bm + wid * 32 + l16) * 256 + qd * 8;
  const float* ar1 = ar0 + 16 * 256;
  bf16x8 a0[8], a1[8];
#pragma unroll
  for (int j = 0; j < 8; ++j) {
    a0[j] = cvt8pk(*(const float4*)(ar0 + j * 32), *(const float4*)(ar0 + j * 32 + 4));
    a1[j] = cvt8pk(*(const float4*)(ar1 + j * 32), *(const float4*)(ar1 + j * 32 + 4));
  }
  __syncthreads(); // drains vmcnt: B staged; A regs resident

  f32x4 acc[2][4] = {};
#pragma unroll
  for (int j = 0; j < 8; ++j) {
    const unsigned short* bt = Bs + j * 2048 + l16 * 32 + qd * 8;
#pragma unroll
    for (int ni = 0; ni < 4; ++ni) {
      const bf16x8 bf = *(const bf16x8*)(bt + ni * 512);
      acc[0][ni] = __builtin_amdgcn_mfma_f32_16x16x32_bf16(a0[j], bf, acc[0][ni], 0, 0, 0);
      acc[1][ni] = __builtin_amdgcn_mfma_f32_16x16x32_bf16(a1[j], bf, acc[1][ni], 0, 0, 0);
    }
  }
  // C/D layout: col = lane&15, row = (lane>>4)*4 + reg [m89-verified]
  if (isv) {
#pragma unroll
    for (int ni = 0; ni < 4; ++ni) {
      const int c = bn + ni * 16 + l16;
      const float bb = vp_b[c];
      const int h = c >> 5, d = c & 31;
#pragma unroll
      for (int mi = 0; mi < 2; ++mi)
#pragma unroll
        for (int rr = 0; rr < 4; ++rr) {
          const int gm = bm + wid * 32 + mi * 16 + qd * 4 + rr;
          const int b = gm / NQ, pix = gm - b * NQ;
          v_bf[((size_t)(b * NH + h) * NQ + pix) * HD + d] = f2bf(acc[mi][ni][rr] + bb);
        }
    }
  } else {
#pragma unroll
    for (int ni = 0; ni < 4; ++ni) {
      const int c = bn + ni * 16 + l16;
      const float bb = biasq[c];
#pragma unroll
      for (int mi = 0; mi < 2; ++mi)
#pragma unroll
        for (int rr = 0; rr < 4; ++rr) {
          const int gm = bm + wid * 32 + mi * 16 + qd * 4 + rr;
          offaw_h[(size_t)gm * 384 + c] = (f16)(acc[mi][ni][rr] + bb);
        }
    }
  }
}

// ---------------- GEMM3: out = attn_bf @ out_w^T + out_b (fp32), A-prefetch
__global__ __launch_bounds__(256) void gemm_out_kernel(
    const unsigned short* __restrict__ attn_bf, const unsigned short* __restrict__ wt_out,
    const float* __restrict__ out_b, float* __restrict__ out) {
  __shared__ unsigned short Bs[8 * 64 * 32];
  const int t = threadIdx.x;
  const int lane = t & 63, wid = t >> 6;
  const int qd = lane >> 4, l16 = lane & 15;
  const int g = blockIdx.x;
  const int grp = g / 32, r = g % 32;
  int by, bx;
  if (grp < 21) { by = grp * 8 + (r & 7); bx = r >> 3; }
  else          { by = 168 + (r & 1);     bx = r >> 1; }
  const int bm = by * 128, bn = bx * 64;

  const unsigned short* bg = wt_out + (size_t)(bn + (t >> 2)) * 256 + (t & 3) * 8;
  unsigned short* bs_b = Bs + (t & 192) * 8;
#pragma unroll
  for (int j = 0; j < 8; ++j)
    __builtin_amdgcn_global_load_lds(
        (const __attribute__((address_space(1))) void*)(bg + j * 32),
        (__attribute__((address_space(3))) void*)(bs_b + j * 2048), 16, 0, 0);

  const unsigned short* ar0 = attn_bf + (size_t)(bm + wid * 32 + l16) * 256 + qd * 8;
  const unsigned short* ar1 = ar0 + 16 * 256;
  bf16x8 a0[8], a1[8];
#pragma unroll
  for (int j = 0; j < 8; ++j) {
    a0[j] = *(const bf16x8*)(ar0 + j * 32);
    a1[j] = *(const bf16x8*)(ar1 + j * 32);
  }
  __syncthreads();

  f32x4 acc[2][4] = {};
#pragma unroll
  for (int j = 0; j < 8; ++j) {
    const unsigned short* bt = Bs + j * 2048 + l16 * 32 + qd * 8;
#pragma unroll
    for (int ni = 0; ni < 4; ++ni) {
      const bf16x8 bf = *(const bf16x8*)(bt + ni * 512);
      acc[0][ni] = __builtin_amdgcn_mfma_f32_16x16x32_bf16(a0[j], bf, acc[0][ni], 0, 0, 0);
      acc[1][ni] = __builtin_amdgcn_mfma_f32_16x16x32_bf16(a1[j], bf, acc[1][ni], 0, 0, 0);
    }
  }
#pragma unroll
  for (int ni = 0; ni < 4; ++ni) {
    const int c = bn + ni * 16 + l16;
    const float bb = out_b[c];
#pragma unroll
    for (int mi = 0; mi < 2; ++mi)
#pragma unroll
      for (int rr = 0; rr < 4; ++rr) {
        const int gm = bm + wid * 32 + mi * 16 + qd * 4 + rr;
        out[(size_t)gm * 256 + c] = acc[mi][ni][rr] + bb;
      }
  }
}

// ---------------- Fused softmax + precompute-then-gather deformable sampling
// (round-7 proven version, unchanged)
__global__ __launch_bounds__(256) void sample_fused_kernel(
    const unsigned short* __restrict__ v, const float* __restrict__ refp,
    const f16* __restrict__ offaw_h, unsigned short* __restrict__ out) {
  __shared__ float s_off[8 * 384];          // 12 KB (cols 256..384 = logits)
  __shared__ float s_ref[64];
  __shared__ unsigned s_offs[16 * 64 * 4];  // 16 KB, [p][qh][c]
  __shared__ float s_wts[16 * 64 * 4];      // 16 KB
  const int t = threadIdx.x;
  // XCD swizzle: xcd = blk&7, batch = xcd>>1 (per-batch v is 2.75 MB < 4 MB L2/XCD)
  const int blk = blockIdx.x;
  const int b = (blk & 7) >> 1;
  const int q0loc = ((blk >> 3) * 2 + (blk & 1)) * 8;
  const int q0 = b * NQ + q0loc;

  { // phase 1: stage f16 rows -> fp32 LDS. 3072 halves = 1536 uints, 6/thread
    const unsigned* src = (const unsigned*)(offaw_h + (size_t)q0 * 384);
#pragma unroll
    for (int i = 0; i < 6; ++i) {
      const int idx = t + i * 256;
      union { unsigned u; f16 h[2]; } cv; cv.u = src[idx];
      s_off[2 * idx]     = (float)cv.h[0];
      s_off[2 * idx + 1] = (float)cv.h[1];
    }
    if (t < 64) s_ref[t] = refp[(size_t)q0 * 8 + t];
  }
  __syncthreads();
  if (t < 64) { // phase 2: softmax, 64 groups of 16
    float* p = s_off + (t >> 3) * 384 + 256 + (t & 7) * 16;
    float m = -1e30f;
#pragma unroll
    for (int j = 0; j < 16; ++j) m = fmaxf(m, p[j]);
    float e[16]; float s = 0.f;
#pragma unroll
    for (int j = 0; j < 16; ++j) { e[j] = __expf(p[j] - m); s += e[j]; }
    const float inv = 1.f / s;
#pragma unroll
    for (int j = 0; j < 16; ++j) p[j] = e[j] * inv;
  }
  __syncthreads();
  { // phase 3: tuples. t -> qh = t&63 (q=qh>>3,h=qh&7), level l = t>>6
    const int qh = t & 63, q = qh >> 3, h = qh & 7, l = t >> 6;
    const int HS[NL]      = {64, 32, 16, 8};
    const int LVL_OFF[NL] = {0, 4096, 5120, 5376};
    const int H = HS[l], W = HS[l];
    const float rx = s_ref[q * 8 + l * 2 + 0];
    const float ry = s_ref[q * 8 + l * 2 + 1];
    const unsigned vbase = (unsigned)(((b * NH + h) * NQ + LVL_OFF[l]) * 64);
#pragma unroll
    for (int pp = 0; pp < 4; ++pp) {
      const int p = l * 4 + pp;
      const float ox = s_off[q * 384 + h * 32 + l * 8 + pp * 2 + 0];
      const float oy = s_off[q * 384 + h * 32 + l * 8 + pp * 2 + 1];
      const float a  = s_off[q * 384 + 256 + h * 16 + p];
      const float px = rx * (float)W + ox - 0.5f;
      const float py = ry * (float)H + oy - 0.5f;
      const float x0f = floorf(px), y0f = floorf(py);
      const int x0 = (int)x0f, y0 = (int)y0f;
      const int x1 = x0 + 1, y1 = y0 + 1;
      const float wx = px - x0f, wy = py - y0f;
      const float m_x0 = (x0 >= 0 && x0 < W) ? 1.f : 0.f;
      const float m_x1 = (x1 >= 0 && x1 < W) ? 1.f : 0.f;
      const float m_y0 = (y0 >= 0 && y0 < H) ? 1.f : 0.f;
      const float m_y1 = (y1 >= 0 && y1 < H) ? 1.f : 0.f;
      const int cx0 = min(max(x0, 0), W - 1), cx1 = min(max(x1, 0), W - 1);
      const int cy0 = min(max(y0, 0), H - 1), cy1 = min(max(y1, 0), H - 1);
      const int ti = (p * 64 + qh) * 4;
      uint4 o4;
      o4.x = vbase + (unsigned)((cy0 * W + cx0) * 64);
      o4.y = vbase + (unsigned)((cy0 * W + cx1) * 64);
      o4.z = vbase + (unsigned)((cy1 * W + cx0) * 64);
      o4.w = vbase + (unsigned)((cy1 * W + cx1) * 64);
      float4 w4;
      w4.x = a * (1.f - wx) * (1.f - wy) * m_x0 * m_y0;
      w4.y = a * wx * (1.f - wy) * m_x1 * m_y0;
      w4.z = a * (1.f - wx) * wy * m_x0 * m_y1;
      w4.w = a * wx * wy * m_x1 * m_y1;
      *(uint4*)&s_offs[ti] = o4;
      *(float4*)&s_wts[ti] = w4;
    }
  }
  __syncthreads();
  // phase 4: gather. wave = 2 queries; lane = q1*32 + h*4 + d8
  const int lane = t & 63, wave = t >> 6;
  const int qloc = wave * 2 + (lane >> 5);
  const int h = (lane >> 2) & 7, d8 = lane & 3;
  const int tqh = qloc * 8 + h;
  const char* vB = (const char*)v;
  const int dof = d8 * 16;
  float acc[8] = {};
#pragma unroll 4
  for (int p = 0; p < 16; ++p) {
    const uint4  o4 = *(const uint4*)&s_offs[(p * 64 + tqh) * 4];
    const float4 w4 = *(const float4*)&s_wts[(p * 64 + tqh) * 4];
    const unsigned off[4] = {o4.x, o4.y, o4.z, o4.w};
    const float wt[4] = {w4.x, w4.y, w4.z, w4.w};
#pragma unroll
    for (int c = 0; c < 4; ++c) {
      union { bf16x8 v8; unsigned u[4]; } cc;
      cc.v8 = *(const bf16x8*)(vB + off[c] + dof);
      const float w = wt[c];
#pragma unroll
      for (int k = 0; k < 4; ++k) {
        acc[2 * k]     += w * bits2f(cc.u[k] << 16);
        acc[2 * k + 1] += w * bits2f(cc.u[k] & 0xffff0000u);
      }
    }
  }
  const int bq = q0 + qloc;
  bf16x8 ov;
#pragma unroll
  for (int k = 0; k < 8; ++k) ov[k] = (short)f2bf(acc[k]);
  *(bf16x8*)(out + (size_t)bq * 256 + h * HD + d8 * 8) = ov;
}

extern "C" void kernel_launch(void* const* d_in, const int* in_sizes, int n_in,
                              void* d_out, int out_size, void* d_ws, size_t ws_size,
                              hipStream_t stream) {
  const float* query        = (const float*)d_in[0];
  const float* value        = (const float*)d_in[1];
  const float* refp         = (const float*)d_in[2];
  const float* value_proj_w = (const float*)d_in[3];
  const float* value_proj_b = (const float*)d_in[4];
  const float* offsets_w    = (const float*)d_in[5];
  const float* offsets_b    = (const float*)d_in[6];
  const float* attn_w_w     = (const float*)d_in[7];
  const float* attn_w_b     = (const float*)d_in[8];
  const float* out_w        = (const float*)d_in[9];
  const float* out_b        = (const float*)d_in[10];
  float* out = (float*)d_out;

  const int M = M_ROWS; // 21760
  const size_t SZ_V   = (size_t)M * 256 * 2; // 11.1 MB
  const size_t SZ_OFF = (size_t)M * 384 * 2; // 16.7 MB
  char* w = (char*)d_ws;
  unsigned short* v_bf    = (unsigned short*)w;                // head-major
  unsigned short* attn_bf = (unsigned short*)(w + SZ_V);
  f16* offaw_h            = (f16*)(w + 2 * SZ_V);
  char* wts               = w + 2 * SZ_V + SZ_OFF;
  unsigned short* wt_vp   = (unsigned short*)wts;              // 256*256
  unsigned short* wt_q    = wt_vp + 65536;                     // 384*256
  unsigned short* wt_out  = wt_q + 98304;                      // 256*256
  float* biasq            = (float*)(wt_out + 65536);          // 384

  dim3 blk(256);
  prep_weights<<<898, blk, 0, stream>>>(value_proj_w, offsets_w, attn_w_w, out_w,
                                        offsets_b, attn_w_b,
                                        wt_vp, wt_q, wt_out, biasq);
  // merged value-proj (bx 0-3, head-major bf16 v) + offsets/logits (bx 4-9, f16)
  // reads fp32 value/query directly, converts in-register pre-barrier
  gemm12_kernel<<<1700, blk, 0, stream>>>(
      value, query, wt_vp, wt_q, value_proj_b, biasq, v_bf, offaw_h);
  // fused softmax + sampling (XCD-swizzled) -> bf16
  sample_fused_kernel<<<M / 8, blk, 0, stream>>>(v_bf, refp, offaw_h, attn_bf);
  // output projection -> fp32 out
  gemm_out_kernel<<<680, blk, 0, stream>>>(attn_bf, wt_out, out_b, out);
}

// Round 12
// 173.597 us; speedup vs baseline: 1.0447x; 1.0447x over previous
//
#include <hip/hip_runtime.h>
#include <hip/hip_bf16.h>
#include <math.h>

// Problem constants
#define B_ 4
#define NQ 5440          // 64*64 + 32*32 + 16*16 + 8*8
#define M_ROWS (B_ * NQ) // 21760
#define NH 8
#define NL 4
#define NP 4
#define HD 32

typedef __attribute__((ext_vector_type(8))) short bf16x8; // 8 bf16 (4 VGPRs)
typedef __attribute__((ext_vector_type(4))) short bf16x4; // 8 bytes
typedef __attribute__((ext_vector_type(4))) float f32x4;
typedef _Float16 f16;

static __device__ __forceinline__ unsigned short f2bf(float f) {
  union { float f; unsigned u; } v; v.f = f;
  unsigned r = (v.u + 0x7fffu + ((v.u >> 16) & 1u)) >> 16; // RNE
  return (unsigned short)r;
}
static __device__ __forceinline__ float bits2f(unsigned u) {
  union { unsigned u; float f; } v; v.u = u; return v.f;
}

// ---------------- merged prep: fp32->bf16 of value+query + weight transpose/convert
__global__ __launch_bounds__(256) void prep_all(
    const float* __restrict__ value, const float* __restrict__ query,
    unsigned short* __restrict__ value_bf, unsigned short* __restrict__ query_bf,
    const float* __restrict__ vpw, const float* __restrict__ offw,
    const float* __restrict__ attnw, const float* __restrict__ outw,
    const float* __restrict__ offb, const float* __restrict__ attnb,
    unsigned short* __restrict__ vp_t, unsigned short* __restrict__ q_t,
    unsigned short* __restrict__ out_t, float* __restrict__ biasq, int n4) {
  int id = blockIdx.x * 256 + threadIdx.x;
  if (id < 2 * n4) { // conversion part
    const float* src; unsigned short* dst; int j;
    if (id < n4) { src = value; dst = value_bf; j = id; }
    else { src = query; dst = query_bf; j = id - n4; }
    float4 f = ((const float4*)src)[j];
    bf16x4 o;
    o[0] = (short)f2bf(f.x); o[1] = (short)f2bf(f.y);
    o[2] = (short)f2bf(f.z); o[3] = (short)f2bf(f.w);
    ((bf16x4*)dst)[j] = o;
    return;
  }
  int w = id - 2 * n4;
  if (w < 65536) {                        // vp_t[256][256]
    int n = w >> 8, k = w & 255;
    vp_t[w] = f2bf(vpw[k * 256 + n]);
  } else if (w < 163840) {                // q_t[384][256] = [off^T ; attn^T]
    int q = w - 65536; int n = q >> 8, k = q & 255;
    q_t[q] = f2bf(n < 256 ? offw[k * 256 + n] : attnw[k * 128 + (n - 256)]);
  } else if (w < 229376) {                // out_t[256][256]
    int o = w - 163840; int n = o >> 8, k = o & 255;
    out_t[o] = f2bf(outw[k * 256 + n]);
  } else if (w < 229760) {                // biasq[384]
    int j = w - 229376;
    biasq[j] = j < 256 ? offb[j] : attnb[j - 256];
  }
}

// ---------------- GEMM1+2 merged: B-tile in LDS (1 barrier), ALL 16 A-fragments
// register-prefetched BEFORE the barrier (full MLP, overlaps B staging; barrier's
// vmcnt(0) drain covers both). Post-barrier loop = pure ds_read + MFMA.
// Block = 128 M x 64 N; wave = 32 M x 64 N via 2x4 mfma_16x16x32.
__global__ __launch_bounds__(256) void gemm12_kernel(
    const unsigned short* __restrict__ valbf, const unsigned short* __restrict__ qrybf,
    const unsigned short* __restrict__ wt_vp, const unsigned short* __restrict__ wt_q,
    const float* __restrict__ vp_b, const float* __restrict__ biasq,
    unsigned short* __restrict__ v_bf, f16* __restrict__ offaw_h) {
  __shared__ unsigned short Bs[8 * 64 * 32]; // 32 KB: 8 k-tiles of [64 n][32 k]
  const int t = threadIdx.x;
  const int lane = t & 63, wid = t >> 6;
  const int qd = lane >> 4, l16 = lane & 15;
  const int g = blockIdx.x;
  const int grp = g / 80, r = g % 80;
  int by, bx;
  if (grp < 21) { by = grp * 8 + (r & 7); bx = r >> 3; }
  else          { by = 168 + (r & 1);     bx = r >> 1; } // tail: 2 rows x 10 cols
  const int bm = by * 128;
  const bool isv = bx < 4;
  const int bn = isv ? bx * 64 : (bx - 4) * 64;
  const unsigned short* A  = isv ? valbf : qrybf;
  const unsigned short* Wt = isv ? wt_vp : wt_q;

  // stage B tile (weights) via async global->LDS
  const unsigned short* bg = Wt + (size_t)(bn + (t >> 2)) * 256 + (t & 3) * 8;
  unsigned short* bs_b = Bs + (t & 192) * 8;
#pragma unroll
  for (int j = 0; j < 8; ++j)
    __builtin_amdgcn_global_load_lds(
        (const __attribute__((address_space(1))) void*)(bg + j * 32),
        (__attribute__((address_space(3))) void*)(bs_b + j * 2048), 16, 0, 0);

  // prefetch ALL A fragments into registers (16 independent dwordx4 loads)
  const unsigned short* ar0 = A + (size_t)(bm + wid * 32 + l16) * 256 + qd * 8;
  const unsigned short* ar1 = ar0 + 16 * 256;
  bf16x8 a0[8], a1[8];
#pragma unroll
  for (int j = 0; j < 8; ++j) {
    a0[j] = *(const bf16x8*)(ar0 + j * 32);
    a1[j] = *(const bf16x8*)(ar1 + j * 32);
  }
  __syncthreads(); // drains vmcnt: B staged AND A regs resident

  f32x4 acc[2][4] = {};
#pragma unroll
  for (int j = 0; j < 8; ++j) {
    const unsigned short* bt = Bs + j * 2048 + l16 * 32 + qd * 8;
#pragma unroll
    for (int ni = 0; ni < 4; ++ni) {
      const bf16x8 bf = *(const bf16x8*)(bt + ni * 512);
      acc[0][ni] = __builtin_amdgcn_mfma_f32_16x16x32_bf16(a0[j], bf, acc[0][ni], 0, 0, 0);
      acc[1][ni] = __builtin_amdgcn_mfma_f32_16x16x32_bf16(a1[j], bf, acc[1][ni], 0, 0, 0);
    }
  }
  // C/D layout: col = lane&15, row = (lane>>4)*4 + reg [m89-verified]
  if (isv) {
#pragma unroll
    for (int ni = 0; ni < 4; ++ni) {
      const int c = bn + ni * 16 + l16;
      const float bb = vp_b[c];
      const int h = c >> 5, d = c & 31;
#pragma unroll
      for (int mi = 0; mi < 2; ++mi)
#pragma unroll
        for (int rr = 0; rr < 4; ++rr) {
          const int gm = bm + wid * 32 + mi * 16 + qd * 4 + rr;
          const int b = gm / NQ, pix = gm - b * NQ;
          v_bf[((size_t)(b * NH + h) * NQ + pix) * HD + d] = f2bf(acc[mi][ni][rr] + bb);
        }
    }
  } else {
#pragma unroll
    for (int ni = 0; ni < 4; ++ni) {
      const int c = bn + ni * 16 + l16;
      const float bb = biasq[c];
#pragma unroll
      for (int mi = 0; mi < 2; ++mi)
#pragma unroll
        for (int rr = 0; rr < 4; ++rr) {
          const int gm = bm + wid * 32 + mi * 16 + qd * 4 + rr;
          offaw_h[(size_t)gm * 384 + c] = (f16)(acc[mi][ni][rr] + bb);
        }
    }
  }
}

// ---------------- GEMM3: out = attn_bf @ out_w^T + out_b (fp32), same A-prefetch
__global__ __launch_bounds__(256) void gemm_out_kernel(
    const unsigned short* __restrict__ attn_bf, const unsigned short* __restrict__ wt_out,
    const float* __restrict__ out_b, float* __restrict__ out) {
  __shared__ unsigned short Bs[8 * 64 * 32];
  const int t = threadIdx.x;
  const int lane = t & 63, wid = t >> 6;
  const int qd = lane >> 4, l16 = lane & 15;
  const int g = blockIdx.x;
  const int grp = g / 32, r = g % 32;
  int by, bx;
  if (grp < 21) { by = grp * 8 + (r & 7); bx = r >> 3; }
  else          { by = 168 + (r & 1);     bx = r >> 1; }
  const int bm = by * 128, bn = bx * 64;

  const unsigned short* bg = wt_out + (size_t)(bn + (t >> 2)) * 256 + (t & 3) * 8;
  unsigned short* bs_b = Bs + (t & 192) * 8;
#pragma unroll
  for (int j = 0; j < 8; ++j)
    __builtin_amdgcn_global_load_lds(
        (const __attribute__((address_space(1))) void*)(bg + j * 32),
        (__attribute__((address_space(3))) void*)(bs_b + j * 2048), 16, 0, 0);

  const unsigned short* ar0 = attn_bf + (size_t)(bm + wid * 32 + l16) * 256 + qd * 8;
  const unsigned short* ar1 = ar0 + 16 * 256;
  bf16x8 a0[8], a1[8];
#pragma unroll
  for (int j = 0; j < 8; ++j) {
    a0[j] = *(const bf16x8*)(ar0 + j * 32);
    a1[j] = *(const bf16x8*)(ar1 + j * 32);
  }
  __syncthreads();

  f32x4 acc[2][4] = {};
#pragma unroll
  for (int j = 0; j < 8; ++j) {
    const unsigned short* bt = Bs + j * 2048 + l16 * 32 + qd * 8;
#pragma unroll
    for (int ni = 0; ni < 4; ++ni) {
      const bf16x8 bf = *(const bf16x8*)(bt + ni * 512);
      acc[0][ni] = __builtin_amdgcn_mfma_f32_16x16x32_bf16(a0[j], bf, acc[0][ni], 0, 0, 0);
      acc[1][ni] = __builtin_amdgcn_mfma_f32_16x16x32_bf16(a1[j], bf, acc[1][ni], 0, 0, 0);
    }
  }
#pragma unroll
  for (int ni = 0; ni < 4; ++ni) {
    const int c = bn + ni * 16 + l16;
    const float bb = out_b[c];
#pragma unroll
    for (int mi = 0; mi < 2; ++mi)
#pragma unroll
      for (int rr = 0; rr < 4; ++rr) {
        const int gm = bm + wid * 32 + mi * 16 + qd * 4 + rr;
        out[(size_t)gm * 256 + c] = acc[mi][ni][rr] + bb;
      }
  }
}

// ---------------- Fused softmax + precompute-then-gather deformable sampling
// (round-7 proven version: f32 folded weights, no LDS union, 68-VGPR gather MLP)
__global__ __launch_bounds__(256) void sample_fused_kernel(
    const unsigned short* __restrict__ v, const float* __restrict__ refp,
    const f16* __restrict__ offaw_h, unsigned short* __restrict__ out) {
  __shared__ float s_off[8 * 384];          // 12 KB (cols 256..384 = logits)
  __shared__ float s_ref[64];
  __shared__ unsigned s_offs[16 * 64 * 4];  // 16 KB, [p][qh][c]
  __shared__ float s_wts[16 * 64 * 4];      // 16 KB
  const int t = threadIdx.x;
  // XCD swizzle: xcd = blk&7, batch = xcd>>1 (per-batch v is 2.75 MB < 4 MB L2/XCD)
  const int blk = blockIdx.x;
  const int b = (blk & 7) >> 1;
  const int q0loc = ((blk >> 3) * 2 + (blk & 1)) * 8;
  const int q0 = b * NQ + q0loc;

  { // phase 1: stage f16 rows -> fp32 LDS. 3072 halves = 1536 uints, 6/thread
    const unsigned* src = (const unsigned*)(offaw_h + (size_t)q0 * 384);
#pragma unroll
    for (int i = 0; i < 6; ++i) {
      const int idx = t + i * 256;
      union { unsigned u; f16 h[2]; } cv; cv.u = src[idx];
      s_off[2 * idx]     = (float)cv.h[0];
      s_off[2 * idx + 1] = (float)cv.h[1];
    }
    if (t < 64) s_ref[t] = refp[(size_t)q0 * 8 + t];
  }
  __syncthreads();
  if (t < 64) { // phase 2: softmax, 64 groups of 16
    float* p = s_off + (t >> 3) * 384 + 256 + (t & 7) * 16;
    float m = -1e30f;
#pragma unroll
    for (int j = 0; j < 16; ++j) m = fmaxf(m, p[j]);
    float e[16]; float s = 0.f;
#pragma unroll
    for (int j = 0; j < 16; ++j) { e[j] = __expf(p[j] - m); s += e[j]; }
    const float inv = 1.f / s;
#pragma unroll
    for (int j = 0; j < 16; ++j) p[j] = e[j] * inv;
  }
  __syncthreads();
  { // phase 3: tuples. t -> qh = t&63 (q=qh>>3,h=qh&7), level l = t>>6
    const int qh = t & 63, q = qh >> 3, h = qh & 7, l = t >> 6;
    const int HS[NL]      = {64, 32, 16, 8};
    const int LVL_OFF[NL] = {0, 4096, 5120, 5376};
    const int H = HS[l], W = HS[l];
    const float rx = s_ref[q * 8 + l * 2 + 0];
    const float ry = s_ref[q * 8 + l * 2 + 1];
    const unsigned vbase = (unsigned)(((b * NH + h) * NQ + LVL_OFF[l]) * 64);
#pragma unroll
    for (int pp = 0; pp < 4; ++pp) {
      const int p = l * 4 + pp;
      const float ox = s_off[q * 384 + h * 32 + l * 8 + pp * 2 + 0];
      const float oy = s_off[q * 384 + h * 32 + l * 8 + pp * 2 + 1];
      const float a  = s_off[q * 384 + 256 + h * 16 + p];
      const float px = rx * (float)W + ox - 0.5f;
      const float py = ry * (float)H + oy - 0.5f;
      const float x0f = floorf(px), y0f = floorf(py);
      const int x0 = (int)x0f, y0 = (int)y0f;
      const int x1 = x0 + 1, y1 = y0 + 1;
      const float wx = px - x0f, wy = py - y0f;
      const float m_x0 = (x0 >= 0 && x0 < W) ? 1.f : 0.f;
      const float m_x1 = (x1 >= 0 && x1 < W) ? 1.f : 0.f;
      const float m_y0 = (y0 >= 0 && y0 < H) ? 1.f : 0.f;
      const float m_y1 = (y1 >= 0 && y1 < H) ? 1.f : 0.f;
      const int cx0 = min(max(x0, 0), W - 1), cx1 = min(max(x1, 0), W - 1);
      const int cy0 = min(max(y0, 0), H - 1), cy1 = min(max(y1, 0), H - 1);
      const int ti = (p * 64 + qh) * 4;
      uint4 o4;
      o4.x = vbase + (unsigned)((cy0 * W + cx0) * 64);
      o4.y = vbase + (unsigned)((cy0 * W + cx1) * 64);
      o4.z = vbase + (unsigned)((cy1 * W + cx0) * 64);
      o4.w = vbase + (unsigned)((cy1 * W + cx1) * 64);
      float4 w4;
      w4.x = a * (1.f - wx) * (1.f - wy) * m_x0 * m_y0;
      w4.y = a * wx * (1.f - wy) * m_x1 * m_y0;
      w4.z = a * (1.f - wx) * wy * m_x0 * m_y1;
      w4.w = a * wx * wy * m_x1 * m_y1;
      *(uint4*)&s_offs[ti] = o4;
      *(float4*)&s_wts[ti] = w4;
    }
  }
  __syncthreads();
  // phase 4: gather. wave = 2 queries; lane = q1*32 + h*4 + d8
  const int lane = t & 63, wave = t >> 6;
  const int qloc = wave * 2 + (lane >> 5);
  const int h = (lane >> 2) & 7, d8 = lane & 3;
  const int tqh = qloc * 8 + h;
  const char* vB = (const char*)v;
  const int dof = d8 * 16;
  float acc[8] = {};
#pragma unroll 4
  for (int p = 0; p < 16; ++p) {
    const uint4  o4 = *(const uint4*)&s_offs[(p * 64 + tqh) * 4];
    const float4 w4 = *(const float4*)&s_wts[(p * 64 + tqh) * 4];
    const unsigned off[4] = {o4.x, o4.y, o4.z, o4.w};
    const float wt[4] = {w4.x, w4.y, w4.z, w4.w};
#pragma unroll
    for (int c = 0; c < 4; ++c) {
      union { bf16x8 v8; unsigned u[4]; } cc;
      cc.v8 = *(const bf16x8*)(vB + off[c] + dof);
      const float w = wt[c];
#pragma unroll
      for (int k = 0; k < 4; ++k) {
        acc[2 * k]     += w * bits2f(cc.u[k] << 16);
        acc[2 * k + 1] += w * bits2f(cc.u[k] & 0xffff0000u);
      }
    }
  }
  const int bq = q0 + qloc;
  bf16x8 ov;
#pragma unroll
  for (int k = 0; k < 8; ++k) ov[k] = (short)f2bf(acc[k]);
  *(bf16x8*)(out + (size_t)bq * 256 + h * HD + d8 * 8) = ov;
}

extern "C" void kernel_launch(void* const* d_in, const int* in_sizes, int n_in,
                              void* d_out, int out_size, void* d_ws, size_t ws_size,
                              hipStream_t stream) {
  const float* query        = (const float*)d_in[0];
  const float* value        = (const float*)d_in[1];
  const float* refp         = (const float*)d_in[2];
  const float* value_proj_w = (const float*)d_in[3];
  const float* value_proj_b = (const float*)d_in[4];
  const float* offsets_w    = (const float*)d_in[5];
  const float* offsets_b    = (const float*)d_in[6];
  const float* attn_w_w     = (const float*)d_in[7];
  const float* attn_w_b     = (const float*)d_in[8];
  const float* out_w        = (const float*)d_in[9];
  const float* out_b        = (const float*)d_in[10];
  float* out = (float*)d_out;

  const int M = M_ROWS; // 21760
  const size_t SZ_V   = (size_t)M * 256 * 2; // 11.1 MB
  const size_t SZ_OFF = (size_t)M * 384 * 2; // 16.7 MB
  char* w = (char*)d_ws;
  unsigned short* value_bf = (unsigned short*)w;               // consumed by gemm12
  unsigned short* attn_bf  = (unsigned short*)w;               // aliases value_bf
  unsigned short* query_bf = (unsigned short*)(w + SZ_V);
  unsigned short* v_bf     = (unsigned short*)(w + 2 * SZ_V);  // head-major
  f16* offaw_h             = (f16*)(w + 3 * SZ_V);
  char* wts                = w + 3 * SZ_V + SZ_OFF;
  unsigned short* wt_vp    = (unsigned short*)wts;             // 256*256
  unsigned short* wt_q     = wt_vp + 65536;                    // 384*256
  unsigned short* wt_out   = wt_q + 98304;                     // 256*256
  float* biasq             = (float*)(wt_out + 65536);         // 384

  dim3 blk(256);
  const int n4 = M * 64;
  const int prep_blocks = (2 * n4 + 229760 + 255) / 256;
  prep_all<<<prep_blocks, blk, 0, stream>>>(
      value, query, value_bf, query_bf,
      value_proj_w, offsets_w, attn_w_w, out_w, offsets_b, attn_w_b,
      wt_vp, wt_q, wt_out, biasq, n4);
  // merged value-proj (bx 0-3, head-major bf16 v) + offsets/logits (bx 4-9, f16)
  gemm12_kernel<<<1700, blk, 0, stream>>>(
      value_bf, query_bf, wt_vp, wt_q, value_proj_b, biasq, v_bf, offaw_h);
  // fused softmax + sampling (XCD-swizzled) -> bf16
  sample_fused_kernel<<<M / 8, blk, 0, stream>>>(v_bf, refp, offaw_h, attn_bf);
  // output projection -> fp32 out
  gemm_out_kernel<<<680, blk, 0, stream>>>(attn_bf, wt_out, out_b, out);
}